// Round 3
// baseline (517.229 us; speedup 1.0000x reference)
//
#include <hip/hip_runtime.h>
#include <cstdint>

// HungarianMatcher cost via MFMA, round 5 (resubmit: R2 bench was an infra
// failure - "MI355X container failed twice" - kernel never ran).
// R1: LDS-atomic histogram = DS-pipe-bound (815us).
// R2: on-the-fly per-wave B build = 140 VALU/step (240us).
// R3: Bpre precompute (226us): B-load 4x duplicated, 3 waves/SIMD cap.
// R4: block-shared LDS B build, dbuf, 1 barrier/step (199us). Occ 37%,
//     VALU 37%, MFMA 7%, HBM 14% -> still issue/stall bound. Per-wave-step
//     ~1000 VALU cycles: 112 scalar f32 ops + 24 trans (quarter-rate) in
//     point_math + labels L2 latency exposed inside every barrier phase.
// R5 fix: (a) f32x2 packed point_math -> v_pk_{mul,add,fma}_f32 halves the
//     full-rate op count; trans floor = 3/point (exp2, rcp, log2) kept.
//     (b) labels prefetched one step ahead in regs (load issued right after
//     the build that consumed the previous set -> full iteration of slack).
//     (c) loop peeled: no per-iter `more` branches on loads.
//     Reg budget: arch ~72 + 56 acc <= 128 keeps 4 waves/SIMD.

#define FOCAL_ALPHA 0.25f
constexpr int NMAX   = 128;
constexpr int NTILES = 7;      // 7 x 16 = 112 cols >= N=100
constexpr int BLOCK  = 256;    // 4 waves, each owns one 16-row q-strip
constexpr int KC     = 146;    // 146*7 = 1022 blocks ~ 4 blocks/CU, one round

typedef __attribute__((ext_vector_type(8))) short short8;
typedef __attribute__((ext_vector_type(4))) float f32x4;
typedef __attribute__((ext_vector_type(2))) float f32x2;

union BU { uint4 q; short8 v; uint32_t u[4]; };

// Packed point math on 2 points. Per pair: ~14 pk-ops + 6 trans.
// exp2/log2 with explicit ln2 muls == what __expf/__logf lower to.
// Safe for |x| < 80 (inputs ~N(0,1)).
__device__ __forceinline__ void point_math2(f32x2 x, f32x2& d, f32x2& f0o, f32x2& po) {
    f32x2 t = x * (-1.44269504089f);                  // -x * log2(e)
    f32x2 e;                                          // e^{-x}
    e.x = __builtin_amdgcn_exp2f(t.x);
    e.y = __builtin_amdgcn_exp2f(t.y);
    f32x2 a = e + 1.0f;
    f32x2 p;                                          // sigmoid(x)
    p.x = __builtin_amdgcn_rcpf(a.x);
    p.y = __builtin_amdgcn_rcpf(a.y);
    f32x2 L;                                          // log2(1+e^-x)
    L.x = __builtin_amdgcn_logf(a.x);
    L.y = __builtin_amdgcn_logf(a.y);
    f32x2 l  = L * 0.69314718056f;                    // -log p
    f32x2 lm = L * (-0.69314718056f) - x;             // log(1-p) = -x - l (pk_fma)
    f32x2 om = e * p;                                 // 1 - p
    f32x2 f1 = (om * om) * (l * FOCAL_ALPHA);         // alpha (1-p)^2 (-log p)
    f32x2 f0 = (p * p) * (lm * -(1.0f - FOCAL_ALPHA));
    d   = f1 - f0;
    f0o = f0;
    po  = p;
}

// pack two fp32 into bf16x2 by truncation, single v_perm
__device__ __forceinline__ uint32_t pack_bf16_trunc(float lo, float hi) {
    return __builtin_amdgcn_perm(__float_as_uint(hi), __float_as_uint(lo), 0x07060302u);
}

__global__ __launch_bounds__(BLOCK, 4) void
matcher_main(const float* __restrict__ pred, const int* __restrict__ labels,
             float* __restrict__ S1, float* __restrict__ S2,
             float* __restrict__ sumf0, float* __restrict__ sump,
             int Q, int P, int N) {
    // double-buffered shared B fragments: [buf][tile][lane] = uint4 (8 bf16)
    __shared__ uint4 Bl[2][NTILES][64];

    const int tid  = threadIdx.x;
    const int wave = tid >> 6;
    const int lane = tid & 63;
    const int m    = lane & 15;
    const int quad = lane >> 4;

    const int strip = blockIdx.y * 4 + wave;
    const int q0    = strip * 16;
    const bool alive = (q0 < Q);           // wave-uniform; dead waves still
                                           // build B + hit barriers

    const int total_steps = P >> 5;
    const int per         = (total_steps + KC - 1) / KC;
    const int s0          = blockIdx.x * per;
    const int s1          = min(s0 + per, total_steps);
    if (s0 >= s1) return;                  // block-uniform: no barrier reached
    const int nsteps = s1 - s0;

    // tile assignment for the shared B build: wave w builds tiles w, w+4
    const int  t0   = wave;
    const int  t1   = wave + 4;
    const bool has2 = (t1 < NTILES);
    const int  tgt0 = t0 * 16 + m;
    const int  tgt1 = t1 * 16 + m;

    const int*   lr = labels + (size_t)s0 * 32 + quad * 8;
    const float* pr = pred + (size_t)(q0 + m) * P + quad * 8 + (size_t)s0 * 32;

    f32x4 c1[NTILES], c2[NTILES];
    #pragma unroll
    for (int t = 0; t < NTILES; ++t) {
        c1[t] = (f32x4){0.f, 0.f, 0.f, 0.f};
        c2[t] = (f32x4){0.f, 0.f, 0.f, 0.f};
    }
    f32x2 sf2 = (f32x2){0.f, 0.f};
    f32x2 sp2 = (f32x2){0.f, 0.f};

    // Build B fragments (one-hot bf16) from register labels into LDS `buf`.
    // Layout: lane (m,quad), reg i = points quad*8 + {2i,2i+1} (R3-verified).
    auto build = [&](int4 l0, int4 l1, int buf) {
        const int ls[8] = {l0.x, l0.y, l0.z, l0.w, l1.x, l1.y, l1.z, l1.w};
        BU B0;
        #pragma unroll
        for (int i = 0; i < 4; ++i) {
            uint32_t lo = (ls[2*i]   == tgt0) ? 0x00003F80u : 0u;
            uint32_t hi = (ls[2*i+1] == tgt0) ? 0x3F800000u : 0u;
            B0.u[i] = lo | hi;
        }
        Bl[buf][t0][lane] = B0.q;
        if (has2) {
            BU B1;
            #pragma unroll
            for (int i = 0; i < 4; ++i) {
                uint32_t lo = (ls[2*i]   == tgt1) ? 0x00003F80u : 0u;
                uint32_t hi = (ls[2*i+1] == tgt1) ? 0x3F800000u : 0u;
                B1.u[i] = lo | hi;
            }
            Bl[buf][t1][lane] = B1.q;
        }
    };

    // Prologue: build step 0 directly; prefetch step-1 labels into regs.
    {
        int4 a0 = *(const int4*)lr;
        int4 a1 = *(const int4*)(lr + 4);
        build(a0, a1, 0);
    }
    int4 cl0 = (int4){0,0,0,0}, cl1 = (int4){0,0,0,0};
    if (nsteps > 1) {
        lr += 32;
        cl0 = *(const int4*)lr;
        cl1 = *(const int4*)(lr + 4);
    }
    float4 cx0, cx1;
    if (alive) {
        cx0 = *(const float4*)pr;
        cx1 = *(const float4*)(pr + 4);
    }
    __syncthreads();

    int ph = 0;
    for (int s = 0; s < nsteps; ++s) {
        const bool more = (s + 1 < nsteps);   // block-uniform

        float4 nx0, nx1;
        if (alive && more) {                  // prefetch next pred step
            nx0 = *(const float4*)(pr + 32);
            nx1 = *(const float4*)(pr + 36);
        }

        if (alive) {
            // packed point math: pairs (cx0.xy, cx0.zw, cx1.xy, cx1.zw)
            BU A1, A2;
            const f32x2 xp[4] = {(f32x2){cx0.x, cx0.y}, (f32x2){cx0.z, cx0.w},
                                 (f32x2){cx1.x, cx1.y}, (f32x2){cx1.z, cx1.w}};
            #pragma unroll
            for (int i = 0; i < 4; ++i) {
                f32x2 d2, f02, p2;
                point_math2(xp[i], d2, f02, p2);
                sf2 += f02;
                sp2 += p2;
                A1.u[i] = pack_bf16_trunc(d2.x, d2.y);
                A2.u[i] = pack_bf16_trunc(p2.x, p2.y);
            }

            #pragma unroll
            for (int t = 0; t < NTILES; ++t) {
                BU B;
                B.q = Bl[ph][t][lane];
                c1[t] = __builtin_amdgcn_mfma_f32_16x16x32_bf16(A1.v, B.v, c1[t], 0, 0, 0);
                c2[t] = __builtin_amdgcn_mfma_f32_16x16x32_bf16(A2.v, B.v, c2[t], 0, 0, 0);
            }
            pr += 32;
            cx0 = nx0; cx1 = nx1;
        }

        if (more) {
            // build step s+1 from prefetched regs, then issue the load for
            // step s+2 (consumed next iteration -> full step of latency slack)
            build(cl0, cl1, ph ^ 1);
            lr += 32;
            if (s + 2 < nsteps) {
                cl0 = *(const int4*)lr;
                cl1 = *(const int4*)(lr + 4);
            }
        }
        __syncthreads();   // Bl[ph] reads drained before next overwrite;
                           // Bl[ph^1] writes visible
        ph ^= 1;
    }

    if (alive) {
        float a = sf2.x + sf2.y;
        float b = sp2.x + sp2.y;
        a += __shfl_xor(a, 16, 64);
        a += __shfl_xor(a, 32, 64);
        b += __shfl_xor(b, 16, 64);
        b += __shfl_xor(b, 32, 64);
        if (lane < 16) {
            unsafeAtomicAdd(&sumf0[q0 + lane], a);
            unsafeAtomicAdd(&sump[q0 + lane], b);
        }

        // C/D layout: col = lane&15 (+16t), row = quad*4 + reg
        #pragma unroll
        for (int t = 0; t < NTILES; ++t) {
            const int col = t * 16 + m;
            if (col < N) {
                #pragma unroll
                for (int r = 0; r < 4; ++r) {
                    const int row = q0 + quad * 4 + r;
                    unsafeAtomicAdd(&S1[(size_t)row * N + col], c1[t][r]);
                    unsafeAtomicAdd(&S2[(size_t)row * N + col], c2[t][r]);
                }
            }
        }
    }
}

__global__ __launch_bounds__(256) void
matcher_counts(const int* __restrict__ labels, int* __restrict__ counts, int P, int N) {
    __shared__ int c[NMAX];
    for (int i = threadIdx.x; i < NMAX; i += 256) c[i] = 0;
    __syncthreads();
    const int stride = gridDim.x * 256;
    for (int i = blockIdx.x * 256 + threadIdx.x; i < P; i += stride)
        atomicAdd(&c[labels[i]], 1);
    __syncthreads();
    for (int j = threadIdx.x; j < N; j += 256)
        if (c[j] != 0) atomicAdd(&counts[j], c[j]);
}

__global__ __launch_bounds__(256) void
matcher_final(const float* __restrict__ S1, const float* __restrict__ S2,
              const float* __restrict__ sumf0, const float* __restrict__ sump,
              const int* __restrict__ counts, float* __restrict__ out,
              int Q, int P, int N) {
    int idx = blockIdx.x * 256 + threadIdx.x;
    if (idx >= Q * N) return;
    int q = idx / N;
    int j = idx - q * N;
    float invP = 1.0f / (float)P;
    float cost_mask = (S1[idx] + sumf0[q]) * invP;
    float cost_dice = 1.0f - (2.0f * S2[idx] + 1.0f) / (sump[q] + (float)counts[j] + 1.0f);
    out[idx] = cost_mask + cost_dice;
}

extern "C" void kernel_launch(void* const* d_in, const int* in_sizes, int n_in,
                              void* d_out, int out_size, void* d_ws, size_t ws_size,
                              hipStream_t stream) {
    const float* pred   = (const float*)d_in[0];
    const int*   labels = (const int*)d_in[1];
    const int P = in_sizes[1];
    const int Q = in_sizes[0] / P;
    const int N = out_size / Q;

    float* S1     = (float*)d_ws;
    float* S2     = S1 + (size_t)Q * N;
    float* sumf0  = S2 + (size_t)Q * N;
    float* sump   = sumf0 + Q;
    int*   counts = (int*)(sump + Q);
    size_t base_bytes = ((size_t)2 * Q * N + 2 * Q + N) * sizeof(float);

    hipMemsetAsync(d_ws, 0, base_bytes, stream);
    matcher_counts<<<64, 256, 0, stream>>>(labels, counts, P, N);

    const int strips = (Q + 15) / 16;
    dim3 grid(KC, (strips + 3) / 4);
    matcher_main<<<grid, BLOCK, 0, stream>>>(pred, labels, S1, S2, sumf0, sump, Q, P, N);

    int qn = Q * N;
    matcher_final<<<(qn + 255) / 256, 256, 0, stream>>>(S1, S2, sumf0, sump, counts,
                                                        (float*)d_out, Q, P, N);
}

// Round 4
// 469.410 us; speedup vs baseline: 1.1019x; 1.1019x over previous
//
#include <hip/hip_runtime.h>
#include <hip/hip_fp16.h>
#include <cstdint>

// HungarianMatcher cost via MFMA, round 6.
// R1: LDS-atomic histogram = DS-pipe-bound (815us).
// R2: on-the-fly per-wave B build = 140 VALU/step (240us).
// R3: Bpre precompute (226us): B-load 4x duplicated, 3 waves/SIMD cap.
// R4: block-shared LDS B build, dbuf, 1 barrier/step (199us).
// R5: packed f32x2 math: VALUBusy 37->22.5% but time FLAT (203us) =>
//     NOT issue-bound. Per-step wall ~11.3k cy vs ~2.5k cy issue: stalls.
//     Diagnosis: (a) __syncthreads drains vmcnt(0) every step -> pred
//     prefetch (32-segment scatter, ~900cy loaded latency) convoys the
//     whole block 43x; (b) 13M same-line f32 atomics into 320KB at kernel
//     end = serialized memory-side tail.
// R6 fix: (a) raw s_barrier + lgkmcnt(0)-only drain (LDS handoff needs
//     lgkm only; wave-private VMEM rides across barriers - m201 pattern).
//     (b) atomics -> per-chunk partials: c1 f32 (29.3MB) + c2 f16x2-RNE
//     (14.7MB) = 44.0MB (fits proven >=45.1MB ws) + reduce kernel.

#define FOCAL_ALPHA 0.25f
constexpr int NMAX   = 128;
constexpr int NTILES = 7;      // 7 x 16 = 112 cols >= N=100
constexpr int BLOCK  = 256;    // 4 waves, each owns one 16-row q-strip
constexpr int KC     = 146;    // 146*7 = 1022 blocks ~ 4 blocks/CU

typedef __attribute__((ext_vector_type(8))) short short8;
typedef __attribute__((ext_vector_type(4))) float f32x4;
typedef __attribute__((ext_vector_type(2))) float f32x2;

union BU  { uint4 q; short8 v; uint32_t u[4]; };
union H2U { __half2 h; uint32_t u; };

// lgkm-only barrier: drains LDS ops (the cross-wave handoff) but lets
// wave-private global loads stay in flight across the barrier.
__device__ __forceinline__ void block_sync_lgkm() {
    asm volatile("s_waitcnt lgkmcnt(0)" ::: "memory");
    __builtin_amdgcn_s_barrier();
}

// Packed point math on 2 points: ~14 pk-ops + 6 trans. Safe for |x| < 80.
__device__ __forceinline__ void point_math2(f32x2 x, f32x2& d, f32x2& f0o, f32x2& po) {
    f32x2 t = x * (-1.44269504089f);                  // -x * log2(e)
    f32x2 e;                                          // e^{-x}
    e.x = __builtin_amdgcn_exp2f(t.x);
    e.y = __builtin_amdgcn_exp2f(t.y);
    f32x2 a = e + 1.0f;
    f32x2 p;                                          // sigmoid(x)
    p.x = __builtin_amdgcn_rcpf(a.x);
    p.y = __builtin_amdgcn_rcpf(a.y);
    f32x2 L;                                          // log2(1+e^-x)
    L.x = __builtin_amdgcn_logf(a.x);
    L.y = __builtin_amdgcn_logf(a.y);
    f32x2 l  = L * 0.69314718056f;                    // -log p
    f32x2 lm = L * (-0.69314718056f) - x;             // log(1-p)
    f32x2 om = e * p;                                 // 1 - p
    f32x2 f1 = (om * om) * (l * FOCAL_ALPHA);
    f32x2 f0 = (p * p) * (lm * -(1.0f - FOCAL_ALPHA));
    d   = f1 - f0;
    f0o = f0;
    po  = p;
}

__device__ __forceinline__ uint32_t pack_bf16_trunc(float lo, float hi) {
    return __builtin_amdgcn_perm(__float_as_uint(hi), __float_as_uint(lo), 0x07060302u);
}

// PART=true : P1 = c1 f32 partials [kc][nstr][7][64x4], P2 = c2 f16x2 [kc][nstr][7][64x2]
// PART=false: P1 = S1 (atomic), P2 = S2 (atomic, cast)
template<bool PART>
__global__ __launch_bounds__(BLOCK, 4) void
matcher_main(const float* __restrict__ pred, const int* __restrict__ labels,
             float* __restrict__ P1, uint32_t* __restrict__ P2,
             float* __restrict__ sumf0, float* __restrict__ sump,
             int Q, int P, int N, int nstr) {
    __shared__ uint4 Bl[2][NTILES][64];   // double-buffered B fragments

    const int tid  = threadIdx.x;
    const int wave = tid >> 6;
    const int lane = tid & 63;
    const int m    = lane & 15;
    const int quad = lane >> 4;

    const int strip = blockIdx.y * 4 + wave;
    const int q0    = strip * 16;
    const bool alive = (q0 < Q);           // wave-uniform

    const int total_steps = P >> 5;
    const int per         = (total_steps + gridDim.x - 1) / gridDim.x;
    const int s0          = blockIdx.x * per;
    const int s1          = min(s0 + per, total_steps);

    if (s0 >= s1) {                        // empty chunk (block-uniform)
        if constexpr (PART) {
            if (alive) {                   // partials must be defined
                const size_t tb = ((size_t)blockIdx.x * nstr + strip) * NTILES;
                float4* o1 = (float4*)P1 + tb * 64 + lane;
                uint2*  o2 = (uint2*)P2  + tb * 64 + lane;
                #pragma unroll
                for (int t = 0; t < NTILES; ++t) {
                    o1[t * 64] = make_float4(0.f, 0.f, 0.f, 0.f);
                    o2[t * 64] = make_uint2(0u, 0u);
                }
            }
        }
        return;
    }
    const int nsteps = s1 - s0;

    // wave w builds tiles w, w+4 of the shared B
    const int  t0   = wave;
    const int  t1   = wave + 4;
    const bool has2 = (t1 < NTILES);
    const int  tgt0 = t0 * 16 + m;
    const int  tgt1 = t1 * 16 + m;

    const int*   lr = labels + (size_t)s0 * 32 + quad * 8;
    const float* pr = pred + (size_t)(q0 + m) * P + quad * 8 + (size_t)s0 * 32;

    f32x4 c1[NTILES], c2[NTILES];
    #pragma unroll
    for (int t = 0; t < NTILES; ++t) {
        c1[t] = (f32x4){0.f, 0.f, 0.f, 0.f};
        c2[t] = (f32x4){0.f, 0.f, 0.f, 0.f};
    }
    f32x2 sf2 = (f32x2){0.f, 0.f};
    f32x2 sp2 = (f32x2){0.f, 0.f};

    auto build = [&](int4 l0, int4 l1, int buf) {
        const int ls[8] = {l0.x, l0.y, l0.z, l0.w, l1.x, l1.y, l1.z, l1.w};
        BU B0;
        #pragma unroll
        for (int i = 0; i < 4; ++i) {
            uint32_t lo = (ls[2*i]   == tgt0) ? 0x00003F80u : 0u;
            uint32_t hi = (ls[2*i+1] == tgt0) ? 0x3F800000u : 0u;
            B0.u[i] = lo | hi;
        }
        Bl[buf][t0][lane] = B0.q;
        if (has2) {
            BU B1;
            #pragma unroll
            for (int i = 0; i < 4; ++i) {
                uint32_t lo = (ls[2*i]   == tgt1) ? 0x00003F80u : 0u;
                uint32_t hi = (ls[2*i+1] == tgt1) ? 0x3F800000u : 0u;
                B1.u[i] = lo | hi;
            }
            Bl[buf][t1][lane] = B1.q;
        }
    };

    // Prologue: build step 0; prefetch step-1 labels; first pred step.
    {
        int4 a0 = *(const int4*)lr;
        int4 a1 = *(const int4*)(lr + 4);
        build(a0, a1, 0);
    }
    int4 cl0 = (int4){0,0,0,0}, cl1 = (int4){0,0,0,0};
    if (nsteps > 1) {
        lr += 32;
        cl0 = *(const int4*)lr;
        cl1 = *(const int4*)(lr + 4);
    }
    float4 cx0, cx1;
    if (alive) {
        cx0 = *(const float4*)pr;
        cx1 = *(const float4*)(pr + 4);
    }
    block_sync_lgkm();

    int ph = 0;
    for (int s = 0; s < nsteps; ++s) {
        const bool more = (s + 1 < nsteps);   // block-uniform

        float4 nx0, nx1;
        if (alive && more) {                  // prefetch next pred step
            nx0 = *(const float4*)(pr + 32);
            nx1 = *(const float4*)(pr + 36);
        }

        if (alive) {
            BU A1, A2;
            const f32x2 xp[4] = {(f32x2){cx0.x, cx0.y}, (f32x2){cx0.z, cx0.w},
                                 (f32x2){cx1.x, cx1.y}, (f32x2){cx1.z, cx1.w}};
            #pragma unroll
            for (int i = 0; i < 4; ++i) {
                f32x2 d2, f02, p2;
                point_math2(xp[i], d2, f02, p2);
                sf2 += f02;
                sp2 += p2;
                A1.u[i] = pack_bf16_trunc(d2.x, d2.y);
                A2.u[i] = pack_bf16_trunc(p2.x, p2.y);
            }

            #pragma unroll
            for (int t = 0; t < NTILES; ++t) {
                BU B;
                B.q = Bl[ph][t][lane];
                c1[t] = __builtin_amdgcn_mfma_f32_16x16x32_bf16(A1.v, B.v, c1[t], 0, 0, 0);
                c2[t] = __builtin_amdgcn_mfma_f32_16x16x32_bf16(A2.v, B.v, c2[t], 0, 0, 0);
            }
            pr += 32;
            cx0 = nx0; cx1 = nx1;
        }

        if (more) {
            build(cl0, cl1, ph ^ 1);
            lr += 32;
            if (s + 2 < nsteps) {
                cl0 = *(const int4*)lr;
                cl1 = *(const int4*)(lr + 4);
            }
        }
        block_sync_lgkm();   // LDS drained; pred/label loads ride across
        ph ^= 1;
    }

    if (alive) {
        float a = sf2.x + sf2.y;
        float b = sp2.x + sp2.y;
        a += __shfl_xor(a, 16, 64);
        a += __shfl_xor(a, 32, 64);
        b += __shfl_xor(b, 16, 64);
        b += __shfl_xor(b, 32, 64);
        if (lane < 16) {
            unsafeAtomicAdd(&sumf0[q0 + lane], a);
            unsafeAtomicAdd(&sump[q0 + lane], b);
        }

        if constexpr (PART) {
            // streamed partial store, fully coalesced (no atomics)
            const size_t tb = ((size_t)blockIdx.x * nstr + strip) * NTILES;
            float4* o1 = (float4*)P1 + tb * 64 + lane;
            uint2*  o2 = (uint2*)P2  + tb * 64 + lane;
            #pragma unroll
            for (int t = 0; t < NTILES; ++t) {
                o1[t * 64] = make_float4(c1[t][0], c1[t][1], c1[t][2], c1[t][3]);
                H2U ha, hb;
                ha.h = __floats2half2_rn(c2[t][0], c2[t][1]);
                hb.h = __floats2half2_rn(c2[t][2], c2[t][3]);
                o2[t * 64] = make_uint2(ha.u, hb.u);
            }
        } else {
            float* S1 = P1;
            float* S2 = (float*)P2;
            #pragma unroll
            for (int t = 0; t < NTILES; ++t) {
                const int col = t * 16 + m;
                if (col < N) {
                    #pragma unroll
                    for (int r = 0; r < 4; ++r) {
                        const int row = q0 + quad * 4 + r;
                        unsafeAtomicAdd(&S1[(size_t)row * N + col], c1[t][r]);
                        unsafeAtomicAdd(&S2[(size_t)row * N + col], c2[t][r]);
                    }
                }
            }
        }
    }
}

// Reduce partials over kc chunks and apply the cost formula.
// grid: (NTILES, strips); 1024 threads: kslice = tid>>8, elem = tid&255.
__global__ __launch_bounds__(1024) void
matcher_reduce(const float* __restrict__ P1, const uint32_t* __restrict__ P2,
               const float* __restrict__ sumf0, const float* __restrict__ sump,
               const int* __restrict__ counts, float* __restrict__ out,
               int Q, int P, int N, int nstr, int kc) {
    __shared__ float R1[4][256];
    __shared__ float R2[4][256];
    const int tid   = threadIdx.x;
    const int ks    = tid >> 8;
    const int el    = tid & 255;
    const int t     = blockIdx.x;
    const int strip = blockIdx.y;
    const int lane  = el >> 2;
    const int r     = el & 3;

    float a1 = 0.f, a2 = 0.f;
    for (int k = ks; k < kc; k += 4) {
        const size_t tb = ((size_t)k * nstr + strip) * NTILES + t;
        a1 += P1[tb * 256 + el];
        H2U h; h.u = P2[tb * 128 + lane * 2 + (r >> 1)];
        a2 += (r & 1) ? __high2float(h.h) : __low2float(h.h);
    }
    R1[ks][el] = a1;
    R2[ks][el] = a2;
    __syncthreads();
    if (tid < 256) {
        a1 = R1[0][el] + R1[1][el] + R1[2][el] + R1[3][el];
        a2 = R2[0][el] + R2[1][el] + R2[2][el] + R2[3][el];
        const int q = strip * 16 + (lane >> 4) * 4 + r;   // C/D row mapping
        const int j = t * 16 + (lane & 15);               // C/D col mapping
        if (q < Q && j < N) {
            float cost_mask = (a1 + sumf0[q]) / (float)P;
            float cost_dice = 1.0f - (2.0f * a2 + 1.0f) / (sump[q] + (float)counts[j] + 1.0f);
            out[q * N + j] = cost_mask + cost_dice;
        }
    }
}

__global__ __launch_bounds__(256) void
matcher_counts(const int* __restrict__ labels, int* __restrict__ counts, int P, int N) {
    __shared__ int c[NMAX];
    for (int i = threadIdx.x; i < NMAX; i += 256) c[i] = 0;
    __syncthreads();
    const int stride = gridDim.x * 256;
    for (int i = blockIdx.x * 256 + threadIdx.x; i < P; i += stride)
        atomicAdd(&c[labels[i]], 1);
    __syncthreads();
    for (int j = threadIdx.x; j < N; j += 256)
        if (c[j] != 0) atomicAdd(&counts[j], c[j]);
}

// fallback final for the atomic path
__global__ __launch_bounds__(256) void
matcher_final(const float* __restrict__ S1, const float* __restrict__ S2,
              const float* __restrict__ sumf0, const float* __restrict__ sump,
              const int* __restrict__ counts, float* __restrict__ out,
              int Q, int P, int N) {
    int idx = blockIdx.x * 256 + threadIdx.x;
    if (idx >= Q * N) return;
    int q = idx / N;
    int j = idx - q * N;
    float invP = 1.0f / (float)P;
    float cost_mask = (S1[idx] + sumf0[q]) * invP;
    float cost_dice = 1.0f - (2.0f * S2[idx] + 1.0f) / (sump[q] + (float)counts[j] + 1.0f);
    out[idx] = cost_mask + cost_dice;
}

extern "C" void kernel_launch(void* const* d_in, const int* in_sizes, int n_in,
                              void* d_out, int out_size, void* d_ws, size_t ws_size,
                              hipStream_t stream) {
    const float* pred   = (const float*)d_in[0];
    const int*   labels = (const int*)d_in[1];
    const int P = in_sizes[1];
    const int Q = in_sizes[0] / P;
    const int N = out_size / Q;

    const int total_steps = P >> 5;
    const int strips = (Q + 15) / 16;
    const int nyb    = (strips + 3) / 4;
    const int nstr   = nyb * 4;

    float* sumf0  = (float*)d_ws;
    float* sump   = sumf0 + Q;
    int*   counts = (int*)(sump + Q);
    size_t hdr = (((size_t)(2 * Q + N)) * sizeof(float) + 255) & ~(size_t)255;

    // per-kc partial bytes: c1 f32 (nstr*7*256*4) + c2 f16x2 (nstr*7*128*4)
    size_t perkc = (size_t)nstr * NTILES * (256 * 4 + 128 * 4);
    int kcmax = (ws_size > hdr) ? (int)((ws_size - hdr) / perkc) : 0;
    int kc = KC < kcmax ? KC : kcmax;
    if (kc > total_steps) kc = total_steps;
    const bool part = (kc >= 8);

    hipMemsetAsync(d_ws, 0, (size_t)(2 * Q + N) * sizeof(float), stream);
    matcher_counts<<<64, 256, 0, stream>>>(labels, counts, P, N);

    if (part) {
        float*    P1 = (float*)((char*)d_ws + hdr);
        uint32_t* P2 = (uint32_t*)(P1 + (size_t)kc * nstr * NTILES * 256);
        matcher_main<true><<<dim3(kc, nyb), BLOCK, 0, stream>>>(
            pred, labels, P1, P2, sumf0, sump, Q, P, N, nstr);
        matcher_reduce<<<dim3(NTILES, strips), 1024, 0, stream>>>(
            P1, P2, sumf0, sump, counts, (float*)d_out, Q, P, N, nstr, kc);
    } else {
        float* S1 = (float*)((char*)d_ws + hdr);
        float* S2 = S1 + (size_t)Q * N;
        hipMemsetAsync(S1, 0, (size_t)2 * Q * N * sizeof(float), stream);
        int kca = KC < total_steps ? KC : total_steps;
        matcher_main<false><<<dim3(kca, nyb), BLOCK, 0, stream>>>(
            pred, labels, S1, (uint32_t*)S2, sumf0, sump, Q, P, N, nstr);
        matcher_final<<<(Q * N + 255) / 256, 256, 0, stream>>>(
            S1, S2, sumf0, sump, counts, (float*)d_out, Q, P, N);
    }
}